// Round 8
// baseline (239.222 us; speedup 1.0000x reference)
//
#include <hip/hip_runtime.h>
#include <hip/hip_bf16.h>
#include <math.h>

// Problem constants (fixed by the reference file)
constexpr int B_   = 2;
constexpr int N_   = 2048;   // T*HS*WS = 8*16*16
constexpr int D_   = 1024;
constexpr int NH_  = 16;
constexpr int NKV_ = 4;
constexpr int HD_  = 64;
constexpr int BN_  = 4096;   // B_*N_
constexpr int KVD_ = NKV_ * HD_;  // 256
constexpr float EPS_ = 1e-6f;
constexpr float THETA_ = 10000.0f;

typedef _Float16 half8v __attribute__((ext_vector_type(8)));
typedef unsigned short ushort8v __attribute__((ext_vector_type(8)));
typedef unsigned short ushort4v __attribute__((ext_vector_type(4)));
typedef float f32x4 __attribute__((ext_vector_type(4)));

static __device__ __forceinline__ unsigned short f2h(float f) {
  union { _Float16 h; unsigned short u; } v; v.h = (_Float16)f; return v.u;
}
static __device__ __forceinline__ float h2f(unsigned short u) {
  union { unsigned short u; _Float16 h; } v; v.u = u; return (float)v.h;
}

// ---------------------------------------------------------------------------
// prep: one launch doing x->f16 cast + all 4 weight transposes (f16; Wo hi/lo
// with x64 pre-scale). Linear block-id partition.
// ---------------------------------------------------------------------------
static __device__ __forceinline__ void wtrans_tile(
    const float* __restrict__ W, int Nw, int K, float scale,
    unsigned short* __restrict__ WTh, unsigned short* __restrict__ WTl,
    int bx, int by, bool lo)
{
  __shared__ float tile[32][33];
  const int k0 = bx * 32, n0 = by * 32;
  const int c = threadIdx.x & 31, rb = threadIdx.x >> 5;
#pragma unroll
  for (int i = 0; i < 4; ++i) {
    const int r = rb + i * 8;
    tile[r][c] = W[(size_t)(k0 + r) * Nw + n0 + c];
  }
  __syncthreads();
#pragma unroll
  for (int i = 0; i < 4; ++i) {
    const int r = rb + i * 8;
    const float v = tile[c][r] * scale;   // = W[k0+c][n0+r] * scale
    const size_t o = (size_t)(n0 + r) * K + k0 + c;
    const unsigned short hi = f2h(v);
    WTh[o] = hi;
    if (lo) WTl[o] = f2h(v - h2f(hi));
  }
}

__global__ __launch_bounds__(256) void prep(
    const float* __restrict__ x,
    const float* __restrict__ Wq, const float* __restrict__ Wk,
    const float* __restrict__ Wv, const float* __restrict__ Wo,
    unsigned short* __restrict__ xh,
    unsigned short* __restrict__ WqT, unsigned short* __restrict__ WkT,
    unsigned short* __restrict__ WvT,
    unsigned short* __restrict__ WoTh, unsigned short* __restrict__ WoTl)
{
  const int bid = blockIdx.x;
  if (bid < 2048) {
    const int i = (bid * 256 + threadIdx.x) * 8;
    const float4 v0 = *(const float4*)(x + i);
    const float4 v1 = *(const float4*)(x + i + 4);
    ushort8v o;
    o[0] = f2h(v0.x); o[1] = f2h(v0.y); o[2] = f2h(v0.z); o[3] = f2h(v0.w);
    o[4] = f2h(v1.x); o[5] = f2h(v1.y); o[6] = f2h(v1.z); o[7] = f2h(v1.w);
    *(ushort8v*)(xh + i) = o;
  } else if (bid < 3072) {
    const int l = bid - 2048;
    wtrans_tile(Wq, D_, D_, 1.0f, WqT, nullptr, l & 31, l >> 5, false);
  } else if (bid < 3328) {
    const int l = bid - 3072;
    wtrans_tile(Wk, KVD_, D_, 1.0f, WkT, nullptr, l & 31, l >> 5, false);
  } else if (bid < 3584) {
    const int l = bid - 3328;
    wtrans_tile(Wv, KVD_, D_, 1.0f, WvT, nullptr, l & 31, l >> 5, false);
  } else {
    const int l = bid - 3584;
    wtrans_tile(Wo, D_, D_, 64.0f, WoTh, WoTl, l & 31, l >> 5, true);
  }
}

// ---------------------------------------------------------------------------
// Fused QKV projection + RMSNorm + 3D RoPE (for Q/K) in the epilogue.
// Single f16 MFMA GEMM, 128x128 tile, BK=32, 256 thr = 4 waves (2x2 of 64x64).
// blockIdx.y: y<8 -> Q, {8,9} -> K, {10,11} -> V. All outputs f16.
// Trig hoisted: t_idx/h_idx constant per mb (no carry from quad*4+r into bit
// 4/8), w_idx = quad*4+r only -> 12 sincos/thread instead of 48.
// ---------------------------------------------------------------------------
__global__ __launch_bounds__(256) void gemm_qkv(
    const unsigned short* __restrict__ xh,
    const unsigned short* __restrict__ WqT, const unsigned short* __restrict__ WkT,
    const unsigned short* __restrict__ WvT,
    const float* __restrict__ bq, const float* __restrict__ bk, const float* __restrict__ bv,
    const float* __restrict__ qn, const float* __restrict__ kn,
    unsigned short* __restrict__ qv, unsigned short* __restrict__ kv,
    unsigned short* __restrict__ vv)
{
  __shared__ unsigned short As[128][40];
  __shared__ unsigned short Bs[128][40];

  const int y = blockIdx.y;
  const unsigned short* wt; const float* bias; unsigned short* outp; int opitch, col0, mode;
  if (y < 8)       { wt = WqT + (size_t)y * 128 * D_;        bias = bq + y * 128;        outp = qv; opitch = D_;   col0 = y * 128;        mode = 0; }
  else if (y < 10) { wt = WkT + (size_t)(y - 8) * 128 * D_;  bias = bk + (y - 8) * 128;  outp = kv; opitch = KVD_; col0 = (y - 8) * 128;  mode = 1; }
  else             { wt = WvT + (size_t)(y - 10) * 128 * D_; bias = bv + (y - 10) * 128; outp = vv; opitch = KVD_; col0 = (y - 10) * 128; mode = 2; }

  const int bm = blockIdx.x * 128;
  const int tid = threadIdx.x;
  const int w = tid >> 6, lane = tid & 63, quad = lane >> 4, l16 = lane & 15;
  const int wm = w & 1, wn = w >> 1;
  const int sr = tid >> 1;          // 0..127 staged row
  const int sk = (tid & 1) * 16;    // 0 / 16

  f32x4 acc[4][4];
#pragma unroll
  for (int i = 0; i < 4; ++i)
#pragma unroll
    for (int j = 0; j < 4; ++j) acc[i][j] = (f32x4){0.f, 0.f, 0.f, 0.f};

  for (int k0 = 0; k0 < D_; k0 += 32) {
    __syncthreads();
    const size_t ga = (size_t)(bm + sr) * D_ + k0 + sk;
    const size_t gb = (size_t)sr * D_ + k0 + sk;
    const ushort8v a0 = *(const ushort8v*)(xh + ga);
    const ushort8v a1 = *(const ushort8v*)(xh + ga + 8);
    const ushort8v b0 = *(const ushort8v*)(wt + gb);
    const ushort8v b1 = *(const ushort8v*)(wt + gb + 8);
    *(ushort8v*)&As[sr][sk]     = a0;
    *(ushort8v*)&As[sr][sk + 8] = a1;
    *(ushort8v*)&Bs[sr][sk]     = b0;
    *(ushort8v*)&Bs[sr][sk + 8] = b1;
    __syncthreads();

    half8v fa[4], fb[4];
#pragma unroll
    for (int mb = 0; mb < 4; ++mb) fa[mb] = *(const half8v*)&As[wm * 64 + mb * 16 + l16][quad * 8];
#pragma unroll
    for (int nb = 0; nb < 4; ++nb) fb[nb] = *(const half8v*)&Bs[wn * 64 + nb * 16 + l16][quad * 8];
#pragma unroll
    for (int mb = 0; mb < 4; ++mb)
#pragma unroll
      for (int nb = 0; nb < 4; ++nb)
        acc[mb][nb] = __builtin_amdgcn_mfma_f32_16x16x32_f16(fa[mb], fb[nb], acc[mb][nb], 0, 0, 0);
  }

  float bsv[4];
#pragma unroll
  for (int nb = 0; nb < 4; ++nb) bsv[nb] = bias[wn * 64 + nb * 16 + l16];

  if (mode == 2) {   // V: bias + cast only
#pragma unroll
    for (int mb = 0; mb < 4; ++mb)
#pragma unroll
      for (int nb = 0; nb < 4; ++nb)
#pragma unroll
        for (int r = 0; r < 4; ++r) {
          const int row = bm + wm * 64 + mb * 16 + quad * 4 + r;
          const int col = col0 + wn * 64 + nb * 16 + l16;
          outp[(size_t)row * opitch + col] = f2h(acc[mb][nb][r] + bsv[nb]);
        }
    return;
  }

  // Q/K: RMSNorm (+learned w) + factored 3D RoPE, fp32 pre-rounding.
  const float* nwp = (mode == 0) ? qn : kn;
  float wv[4];
#pragma unroll
  for (int nb = 0; nb < 4; ++nb) wv[nb] = nwp[nb * 16 + l16];
  const float f_th = __powf(THETA_, -(float)(l16 & 7) / 8.0f);   // t/h segs, dd=16
  const float f_w  = __powf(THETA_, -(float)l16 / 16.0f);        // w seg,  dd=32
  const float oscale = (mode == 0) ? 0.125f : 1.0f;
  const bool first8 = (l16 & 8) == 0;

  float snw[4], csw[4];
#pragma unroll
  for (int r = 0; r < 4; ++r)
    __sincosf((float)(quad * 4 + r) * f_w, &snw[r], &csw[r]);

#pragma unroll
  for (int mb = 0; mb < 4; ++mb) {
    const int nbase = (bm + wm * 64 + mb * 16) & (N_ - 1);
    float snt, cst, snh, csh;
    __sincosf((float)(nbase >> 8) * f_th, &snt, &cst);
    __sincosf((float)((nbase >> 4) & 15) * f_th, &snh, &csh);
#pragma unroll
    for (int r = 0; r < 4; ++r) {
      float v[4];
      float ss = 0.f;
#pragma unroll
      for (int nb = 0; nb < 4; ++nb) { v[nb] = acc[mb][nb][r] + bsv[nb]; ss += v[nb] * v[nb]; }
      ss += __shfl_xor(ss, 1, 64);
      ss += __shfl_xor(ss, 2, 64);
      ss += __shfl_xor(ss, 4, 64);
      ss += __shfl_xor(ss, 8, 64);
      const float rs = rsqrtf(ss * (1.0f / 64.0f) + EPS_);
#pragma unroll
      for (int nb = 0; nb < 4; ++nb) v[nb] *= rs * wv[nb];

      const float p0 = __shfl_xor(v[0], 8, 64);
      const float p1 = __shfl_xor(v[1], 8, 64);
      const float o0 = v[0] * cst + (first8 ? -p0 : p0) * snt;
      const float o1 = v[1] * csh + (first8 ? -p1 : p1) * snh;
      const float o2 = v[2] * csw[r] - v[3] * snw[r];
      const float o3 = v[3] * csw[r] + v[2] * snw[r];

      const int row = bm + wm * 64 + mb * 16 + quad * 4 + r;
      const size_t ob = (size_t)row * opitch + col0 + wn * 64 + l16;
      outp[ob]      = f2h(o0 * oscale);
      outp[ob + 16] = f2h(o1 * oscale);
      outp[ob + 32] = f2h(o2 * oscale);
      outp[ob + 48] = f2h(o3 * oscale);
    }
  }
}

// ---------------------------------------------------------------------------
// Output projection: A = O (single f16), B = 64*Wo^T as f16 hi+lo (~22 bits).
// 2 MFMAs per frag pair; epilogue multiplies by 1/64 (exact) and adds bias.
// ---------------------------------------------------------------------------
__global__ __launch_bounds__(256) void gemm_o(
    const unsigned short* __restrict__ ag,
    const unsigned short* __restrict__ WTh, const unsigned short* __restrict__ WTl,
    const float* __restrict__ bo, float* __restrict__ out)
{
  __shared__ unsigned short As[128][40];
  __shared__ unsigned short Bh[128][40], Bl[128][40];

  const int bm = blockIdx.x * 128, bn = blockIdx.y * 128;
  const int tid = threadIdx.x;
  const int w = tid >> 6, lane = tid & 63, quad = lane >> 4, l16 = lane & 15;
  const int wm = w & 1, wn = w >> 1;
  const int sr = tid >> 1;
  const int sk = (tid & 1) * 16;

  f32x4 acc[4][4];
#pragma unroll
  for (int i = 0; i < 4; ++i)
#pragma unroll
    for (int j = 0; j < 4; ++j) acc[i][j] = (f32x4){0.f, 0.f, 0.f, 0.f};

  for (int k0 = 0; k0 < D_; k0 += 32) {
    __syncthreads();
    const size_t ga = (size_t)(bm + sr) * D_ + k0 + sk;
    const size_t gb = (size_t)(bn + sr) * D_ + k0 + sk;
    const ushort8v a0  = *(const ushort8v*)(ag + ga);
    const ushort8v a1  = *(const ushort8v*)(ag + ga + 8);
    const ushort8v bh0 = *(const ushort8v*)(WTh + gb);
    const ushort8v bh1 = *(const ushort8v*)(WTh + gb + 8);
    const ushort8v bl0 = *(const ushort8v*)(WTl + gb);
    const ushort8v bl1 = *(const ushort8v*)(WTl + gb + 8);
    *(ushort8v*)&As[sr][sk] = a0;  *(ushort8v*)&As[sr][sk + 8] = a1;
    *(ushort8v*)&Bh[sr][sk] = bh0; *(ushort8v*)&Bh[sr][sk + 8] = bh1;
    *(ushort8v*)&Bl[sr][sk] = bl0; *(ushort8v*)&Bl[sr][sk + 8] = bl1;
    __syncthreads();

    half8v fa[4], fbh[4], fbl[4];
#pragma unroll
    for (int mb = 0; mb < 4; ++mb) fa[mb] = *(const half8v*)&As[wm * 64 + mb * 16 + l16][quad * 8];
#pragma unroll
    for (int nb = 0; nb < 4; ++nb) {
      fbh[nb] = *(const half8v*)&Bh[wn * 64 + nb * 16 + l16][quad * 8];
      fbl[nb] = *(const half8v*)&Bl[wn * 64 + nb * 16 + l16][quad * 8];
    }
#pragma unroll
    for (int mb = 0; mb < 4; ++mb)
#pragma unroll
      for (int nb = 0; nb < 4; ++nb) {
        acc[mb][nb] = __builtin_amdgcn_mfma_f32_16x16x32_f16(fa[mb], fbl[nb], acc[mb][nb], 0, 0, 0);
        acc[mb][nb] = __builtin_amdgcn_mfma_f32_16x16x32_f16(fa[mb], fbh[nb], acc[mb][nb], 0, 0, 0);
      }
  }

  float bsv[4];
#pragma unroll
  for (int nb = 0; nb < 4; ++nb) bsv[nb] = bo[bn + wn * 64 + nb * 16 + l16];
#pragma unroll
  for (int mb = 0; mb < 4; ++mb)
#pragma unroll
    for (int nb = 0; nb < 4; ++nb)
#pragma unroll
      for (int r = 0; r < 4; ++r) {
        const int row = bm + wm * 64 + mb * 16 + quad * 4 + r;
        const int col = bn + wn * 64 + nb * 16 + l16;
        out[(size_t)row * D_ + col] = acc[mb][nb][r] * 0.015625f + bsv[nb];
      }
}

// ---------------------------------------------------------------------------
// MFMA flash attention, all-f16, no-max softmax, SPLIT-K x2: each block does
// 16 of the 32 k-tiles for its (b,h,q-tile), writing UNNORMALIZED O (f16) and
// l (f32) partials. Grid 1024 -> 4 blocks/CU = 16 waves/CU (vs 8 at r7),
// keeping r7's halved-LDS-traffic wave structure (4 waves x 32 q-rows).
// Merge is exact: O = O0+O1, l = l0+l1 (no max tracking to reconcile).
// ---------------------------------------------------------------------------
__global__ __launch_bounds__(256) void attn_mfma(
    const unsigned short* __restrict__ qg,
    const unsigned short* __restrict__ kg,
    const unsigned short* __restrict__ vg,
    unsigned short* __restrict__ Opg,   // [half][b][n][D] f16 unnormalized
    float* __restrict__ lpg)            // [half][b][h][n] f32
{
  __shared__ unsigned short Ks[64][72];
  __shared__ unsigned short Vt[64][72];      // [dim][key']
  __shared__ unsigned short Pw[4][32][72];   // per-wave P, [qrow 0..31][key']

  const int bid  = blockIdx.x;
  const int half = bid & 1;
  const int qt   = (bid >> 1) & 15;
  const int h    = (bid >> 5) & 15;
  const int b    = bid >> 9;
  const int kvh  = h >> 2;           // GQA: q-head h -> kv-head h/4

  const int tid  = threadIdx.x;
  const int w    = tid >> 6;         // 0..3
  const int lane = tid & 63;
  const int quad = lane >> 4;
  const int l16  = lane & 15;

  // Q A-frags for 2 query sets (A[m=l16][k=quad*8+j]); 0.125 already in q.
  half8v aq[2][2];
#pragma unroll
  for (int qb = 0; qb < 2; ++qb) {
    const int qrow = qt * 128 + w * 32 + qb * 16 + l16;
    const unsigned short* qptr =
        qg + ((size_t)(b * N_ + qrow) * D_) + h * HD_ + quad * 8;
    aq[qb][0] = *(const half8v*)(qptr);
    aq[qb][1] = *(const half8v*)(qptr + 32);
  }

  f32x4 o[2][4];
  float lrow[2][4];
#pragma unroll
  for (int qb = 0; qb < 2; ++qb)
#pragma unroll
    for (int i = 0; i < 4; ++i) { o[qb][i] = (f32x4){0.f, 0.f, 0.f, 0.f}; lrow[qb][i] = 0.f; }

  // K staging: row = tid>>2, 16-dim segment = (tid&3)*16 (2 b128 per thread)
  const int srow = tid >> 2;
  const int sseg = (tid & 3) << 4;
  // V staging: keys vj+32vh & +16 -> key' cols 4vj+2vh(+1); dims 8vs..+7
  const int vj = tid & 15;
  const int vh = (tid >> 4) & 1;
  const int vs = tid >> 5;           // 0..7

  const int kt0 = half * 16;
  for (int kt = kt0; kt < kt0 + 16; ++kt) {
    __syncthreads();
    {
      const unsigned short* ksrc =
          kg + (size_t)(b * N_ + kt * 64 + srow) * KVD_ + kvh * HD_ + sseg;
      *(ushort8v*)&Ks[srow][sseg]     = *(const ushort8v*)(ksrc);
      *(ushort8v*)&Ks[srow][sseg + 8] = *(const ushort8v*)(ksrc + 8);

      const unsigned short* v1 =
          vg + (size_t)(b * N_ + kt * 64 + vj + 32 * vh) * KVD_ + kvh * HD_ + 8 * vs;
      const ushort8v va = *(const ushort8v*)(v1);
      const ushort8v vb8 = *(const ushort8v*)(v1 + 16 * KVD_);
#pragma unroll
      for (int i = 0; i < 8; ++i)
        *(unsigned int*)&Vt[8 * vs + i][4 * vj + 2 * vh] =
            (unsigned int)va[i] | ((unsigned int)vb8[i] << 16);
    }
    __syncthreads();

    // S = Q K^T (orig key order); K-frags shared across both query sets
    f32x4 s[2][4];
#pragma unroll
    for (int nb = 0; nb < 4; ++nb) {
      const half8v b0 = *(const half8v*)&Ks[nb * 16 + l16][quad * 8];
      const half8v b1 = *(const half8v*)&Ks[nb * 16 + l16][32 + quad * 8];
#pragma unroll
      for (int qb = 0; qb < 2; ++qb) {
        f32x4 z = (f32x4){0.f, 0.f, 0.f, 0.f};
        z = __builtin_amdgcn_mfma_f32_16x16x32_f16(aq[qb][0], b0, z, 0, 0, 0);
        s[qb][nb] = __builtin_amdgcn_mfma_f32_16x16x32_f16(aq[qb][1], b1, z, 0, 0, 0);
      }
    }

    // p = exp(s) directly (bounded); pack 4 keys' -> one b64 per row
#pragma unroll
    for (int qb = 0; qb < 2; ++qb)
#pragma unroll
      for (int r = 0; r < 4; ++r) {
        const float p0 = __expf(s[qb][0][r]);
        const float p1 = __expf(s[qb][1][r]);
        const float p2 = __expf(s[qb][2][r]);
        const float p3 = __expf(s[qb][3][r]);
        lrow[qb][r] += (p0 + p1) + (p2 + p3);
        uint2 u;
        u.x = (unsigned int)f2h(p0) | ((unsigned int)f2h(p1) << 16);
        u.y = (unsigned int)f2h(p2) | ((unsigned int)f2h(p3) << 16);
        *(uint2*)&Pw[w][qb * 16 + quad * 4 + r][4 * l16] = u;
      }

    // O += P V (key' order); V-frags shared across both query sets
#pragma unroll
    for (int kc = 0; kc < 2; ++kc) {
      half8v ap[2];
#pragma unroll
      for (int qb = 0; qb < 2; ++qb)
        ap[qb] = *(const half8v*)&Pw[w][qb * 16 + l16][kc * 32 + quad * 8];
#pragma unroll
      for (int nb = 0; nb < 4; ++nb) {
        const half8v bv = *(const half8v*)&Vt[nb * 16 + l16][kc * 32 + quad * 8];
#pragma unroll
        for (int qb = 0; qb < 2; ++qb)
          o[qb][nb] = __builtin_amdgcn_mfma_f32_16x16x32_f16(ap[qb], bv, o[qb][nb], 0, 0, 0);
      }
    }
  }

  // epilogue: reduce l over l16 groups, store partials (no normalization)
#pragma unroll
  for (int qb = 0; qb < 2; ++qb) {
    const int row0 = qt * 128 + w * 32 + qb * 16 + quad * 4;
#pragma unroll
    for (int r = 0; r < 4; ++r) {
      float lr = lrow[qb][r];
      lr += __shfl_xor(lr, 1, 64);
      lr += __shfl_xor(lr, 2, 64);
      lr += __shfl_xor(lr, 4, 64);
      lr += __shfl_xor(lr, 8, 64);
      if (l16 == 0)
        lpg[((size_t)(half * 2 + b) * NH_ + h) * N_ + row0 + r] = lr;
    }
    const size_t obase = (size_t)half * BN_ * D_ +
        ((size_t)(b * N_ + row0) * D_) + h * HD_ + l16;
#pragma unroll
    for (int r = 0; r < 4; ++r)
#pragma unroll
      for (int nb = 0; nb < 4; ++nb)
        Opg[obase + (size_t)r * D_ + nb * 16] = f2h(o[qb][nb][r]);
  }
}

// ---------------------------------------------------------------------------
// combine: og = (O0 + O1) / (l0 + l1). Elementwise, 8 f16/thread.
// ---------------------------------------------------------------------------
__global__ __launch_bounds__(256) void combine(
    const unsigned short* __restrict__ Opg, const float* __restrict__ lpg,
    unsigned short* __restrict__ og)
{
  const size_t i = ((size_t)blockIdx.x * 256 + threadIdx.x) * 8;
  const int b = (int)(i >> 21);
  const int n = (int)(i >> 10) & (N_ - 1);
  const int h = (int)(i >> 6) & 15;
  const float l0 = lpg[((size_t)b * NH_ + h) * N_ + n];
  const float l1 = lpg[((size_t)(2 + b) * NH_ + h) * N_ + n];
  const float inv = 1.0f / (l0 + l1);
  const ushort8v o0 = *(const ushort8v*)(Opg + i);
  const ushort8v o1 = *(const ushort8v*)(Opg + (size_t)BN_ * D_ + i);
  ushort8v o;
#pragma unroll
  for (int j = 0; j < 8; ++j) o[j] = f2h((h2f(o0[j]) + h2f(o1[j])) * inv);
  *(ushort8v*)(og + i) = o;
}

// ---------------------------------------------------------------------------
extern "C" void kernel_launch(void* const* d_in, const int* in_sizes, int n_in,
                              void* d_out, int out_size, void* d_ws, size_t ws_size,
                              hipStream_t stream) {
  const float* x  = (const float*)d_in[0];
  const float* Wq = (const float*)d_in[1];
  const float* bq = (const float*)d_in[2];
  const float* Wk = (const float*)d_in[3];
  const float* bk = (const float*)d_in[4];
  const float* Wv = (const float*)d_in[5];
  const float* bv = (const float*)d_in[6];
  const float* Wo = (const float*)d_in[7];
  const float* bo = (const float*)d_in[8];
  const float* qn = (const float*)d_in[9];
  const float* kn = (const float*)d_in[10];
  float* out = (float*)d_out;

  // Workspace (u16 units): xh(4M) qv(4M) kv(1M) vv(1M) WqT(1M) WkT(.25M)
  // WvT(.25M) WoTh(1M) WoTl(1M) Op(8M) lp(128K f32) ~= 44 MB.
  // og (combined attention out) aliases xh (dead after gemm_qkv).
  const size_t M4 = (size_t)BN_ * D_;
  const size_t M1 = (size_t)BN_ * KVD_;
  unsigned short* xh  = (unsigned short*)d_ws;
  unsigned short* qv  = xh + M4;
  unsigned short* kv  = qv + M4;
  unsigned short* vv  = kv + M1;
  unsigned short* WqT = vv + M1;
  unsigned short* WkT = WqT + (size_t)D_ * D_;
  unsigned short* WvT = WkT + (size_t)D_ * KVD_;
  unsigned short* WoTh = WvT + (size_t)D_ * KVD_;
  unsigned short* WoTl = WoTh + (size_t)D_ * D_;
  unsigned short* Op  = WoTl + (size_t)D_ * D_;
  float* lp           = (float*)(Op + 2 * M4);
  unsigned short* og  = xh;   // alias

  const dim3 blk(256);

  // 1) cast + all weight transposes in one launch
  prep<<<dim3(4608), blk, 0, stream>>>(x, Wq, Wk, Wv, Wo, xh, WqT, WkT, WvT, WoTh, WoTl);

  // 2) fused QKV projection + RMSNorm + RoPE (q gets 0.125 folded in)
  gemm_qkv<<<dim3(32, 12), blk, 0, stream>>>(xh, WqT, WkT, WvT, bq, bk, bv, qn, kn, qv, kv, vv);

  // 3) split-K all-f16 MFMA flash attention (grid 1024 = 4 blocks/CU)
  attn_mfma<<<dim3(B_ * NH_ * (N_ / 128) * 2), blk, 0, stream>>>(qv, kv, vv, Op, lp);

  // 4) merge the two k-halves: og = (O0+O1)/(l0+l1)
  combine<<<dim3(BN_ * D_ / 2048), blk, 0, stream>>>(Op, lp, og);

  // 5) output projection (A f16 single, B = 64*Wo hi/lo, 2 MFMAs, /64 epilogue)
  gemm_o<<<dim3(32, 8), blk, 0, stream>>>(og, WoTh, WoTl, bo, out);
}

// Round 9
// 225.904 us; speedup vs baseline: 1.0590x; 1.0590x over previous
//
#include <hip/hip_runtime.h>
#include <hip/hip_bf16.h>
#include <math.h>

// Problem constants (fixed by the reference file)
constexpr int B_   = 2;
constexpr int N_   = 2048;   // T*HS*WS = 8*16*16
constexpr int D_   = 1024;
constexpr int NH_  = 16;
constexpr int NKV_ = 4;
constexpr int HD_  = 64;
constexpr int BN_  = 4096;   // B_*N_
constexpr int KVD_ = NKV_ * HD_;  // 256
constexpr float EPS_ = 1e-6f;
constexpr float THETA_ = 10000.0f;

typedef _Float16 half8v __attribute__((ext_vector_type(8)));
typedef unsigned short ushort8v __attribute__((ext_vector_type(8)));
typedef float f32x4 __attribute__((ext_vector_type(4)));

static __device__ __forceinline__ unsigned short f2h(float f) {
  union { _Float16 h; unsigned short u; } v; v.h = (_Float16)f; return v.u;
}
static __device__ __forceinline__ float h2f(unsigned short u) {
  union { unsigned short u; _Float16 h; } v; v.u = u; return (float)v.h;
}

// ---------------------------------------------------------------------------
// prep: one launch doing x->f16 cast + all 4 weight transposes (f16; Wo hi/lo
// with x64 pre-scale). Linear block-id partition.
// ---------------------------------------------------------------------------
static __device__ __forceinline__ void wtrans_tile(
    const float* __restrict__ W, int Nw, int K, float scale,
    unsigned short* __restrict__ WTh, unsigned short* __restrict__ WTl,
    int bx, int by, bool lo)
{
  __shared__ float tile[32][33];
  const int k0 = bx * 32, n0 = by * 32;
  const int c = threadIdx.x & 31, rb = threadIdx.x >> 5;
#pragma unroll
  for (int i = 0; i < 4; ++i) {
    const int r = rb + i * 8;
    tile[r][c] = W[(size_t)(k0 + r) * Nw + n0 + c];
  }
  __syncthreads();
#pragma unroll
  for (int i = 0; i < 4; ++i) {
    const int r = rb + i * 8;
    const float v = tile[c][r] * scale;   // = W[k0+c][n0+r] * scale
    const size_t o = (size_t)(n0 + r) * K + k0 + c;
    const unsigned short hi = f2h(v);
    WTh[o] = hi;
    if (lo) WTl[o] = f2h(v - h2f(hi));
  }
}

__global__ __launch_bounds__(256) void prep(
    const float* __restrict__ x,
    const float* __restrict__ Wq, const float* __restrict__ Wk,
    const float* __restrict__ Wv, const float* __restrict__ Wo,
    unsigned short* __restrict__ xh,
    unsigned short* __restrict__ WqT, unsigned short* __restrict__ WkT,
    unsigned short* __restrict__ WvT,
    unsigned short* __restrict__ WoTh, unsigned short* __restrict__ WoTl)
{
  const int bid = blockIdx.x;
  if (bid < 2048) {
    const int i = (bid * 256 + threadIdx.x) * 8;
    const float4 v0 = *(const float4*)(x + i);
    const float4 v1 = *(const float4*)(x + i + 4);
    ushort8v o;
    o[0] = f2h(v0.x); o[1] = f2h(v0.y); o[2] = f2h(v0.z); o[3] = f2h(v0.w);
    o[4] = f2h(v1.x); o[5] = f2h(v1.y); o[6] = f2h(v1.z); o[7] = f2h(v1.w);
    *(ushort8v*)(xh + i) = o;
  } else if (bid < 3072) {
    const int l = bid - 2048;
    wtrans_tile(Wq, D_, D_, 1.0f, WqT, nullptr, l & 31, l >> 5, false);
  } else if (bid < 3328) {
    const int l = bid - 3072;
    wtrans_tile(Wk, KVD_, D_, 1.0f, WkT, nullptr, l & 31, l >> 5, false);
  } else if (bid < 3584) {
    const int l = bid - 3328;
    wtrans_tile(Wv, KVD_, D_, 1.0f, WvT, nullptr, l & 31, l >> 5, false);
  } else {
    const int l = bid - 3584;
    wtrans_tile(Wo, D_, D_, 64.0f, WoTh, WoTl, l & 31, l >> 5, true);
  }
}

// ---------------------------------------------------------------------------
// Fused QKV projection + RMSNorm + 3D RoPE in the epilogue.
// 128x64 tile (768 blocks = 3/CU), BK=64 (16 iterations, half the barriers).
// 256 thr = 4 waves, ALL in M (32 rows each, full 64-col head per wave) so
// the RMS reduction stays within a wave. blockIdx.y: y<16 -> Q, {16..19} -> K,
// {20..23} -> V. bias pre-offset by col0 -> LOCAL column indexing only.
// ---------------------------------------------------------------------------
__global__ __launch_bounds__(256) void gemm_qkv(
    const unsigned short* __restrict__ xh,
    const unsigned short* __restrict__ WqT, const unsigned short* __restrict__ WkT,
    const unsigned short* __restrict__ WvT,
    const float* __restrict__ bq, const float* __restrict__ bk, const float* __restrict__ bv,
    const float* __restrict__ qn, const float* __restrict__ kn,
    unsigned short* __restrict__ qv, unsigned short* __restrict__ kv,
    unsigned short* __restrict__ vv)
{
  __shared__ unsigned short As[128][72];
  __shared__ unsigned short Bs[64][72];

  const int y = blockIdx.y;
  const unsigned short* wt; const float* bias; unsigned short* outp; int opitch, col0, mode;
  if (y < 16)      { wt = WqT + (size_t)y * 64 * D_;        bias = bq + y * 64;        outp = qv; opitch = D_;   col0 = y * 64;        mode = 0; }
  else if (y < 20) { wt = WkT + (size_t)(y - 16) * 64 * D_; bias = bk + (y - 16) * 64; outp = kv; opitch = KVD_; col0 = (y - 16) * 64; mode = 1; }
  else             { wt = WvT + (size_t)(y - 20) * 64 * D_; bias = bv + (y - 20) * 64; outp = vv; opitch = KVD_; col0 = (y - 20) * 64; mode = 2; }

  const int bm = blockIdx.x * 128;
  const int tid = threadIdx.x;
  const int w = tid >> 6, lane = tid & 63, quad = lane >> 4, l16 = lane & 15;
  const int sa = tid >> 1, ska = (tid & 1) * 32;   // A staging: 128 rows x 64
  const int sb = tid >> 2, skb = (tid & 3) * 16;   // B staging: 64 rows x 64

  f32x4 acc[2][4];
#pragma unroll
  for (int i = 0; i < 2; ++i)
#pragma unroll
    for (int j = 0; j < 4; ++j) acc[i][j] = (f32x4){0.f, 0.f, 0.f, 0.f};

  for (int k0 = 0; k0 < D_; k0 += 64) {
    __syncthreads();
    const size_t ga = (size_t)(bm + sa) * D_ + k0 + ska;
    const size_t gb = (size_t)sb * D_ + k0 + skb;
#pragma unroll
    for (int j = 0; j < 4; ++j)
      *(ushort8v*)&As[sa][ska + 8 * j] = *(const ushort8v*)(xh + ga + 8 * j);
#pragma unroll
    for (int j = 0; j < 2; ++j)
      *(ushort8v*)&Bs[sb][skb + 8 * j] = *(const ushort8v*)(wt + gb + 8 * j);
    __syncthreads();

#pragma unroll
    for (int kk = 0; kk < 2; ++kk) {
      half8v fa[2], fb[4];
#pragma unroll
      for (int mb = 0; mb < 2; ++mb) fa[mb] = *(const half8v*)&As[w * 32 + mb * 16 + l16][kk * 32 + quad * 8];
#pragma unroll
      for (int nb = 0; nb < 4; ++nb) fb[nb] = *(const half8v*)&Bs[nb * 16 + l16][kk * 32 + quad * 8];
#pragma unroll
      for (int mb = 0; mb < 2; ++mb)
#pragma unroll
        for (int nb = 0; nb < 4; ++nb)
          acc[mb][nb] = __builtin_amdgcn_mfma_f32_16x16x32_f16(fa[mb], fb[nb], acc[mb][nb], 0, 0, 0);
    }
  }

  float bsv[4];
#pragma unroll
  for (int nb = 0; nb < 4; ++nb) bsv[nb] = bias[nb * 16 + l16];

  if (mode == 2) {   // V: bias + cast only
#pragma unroll
    for (int mb = 0; mb < 2; ++mb)
#pragma unroll
      for (int nb = 0; nb < 4; ++nb)
#pragma unroll
        for (int r = 0; r < 4; ++r) {
          const int row = bm + w * 32 + mb * 16 + quad * 4 + r;
          outp[(size_t)row * opitch + col0 + nb * 16 + l16] = f2h(acc[mb][nb][r] + bsv[nb]);
        }
    return;
  }

  // Q/K: RMSNorm (+learned w) + factored 3D RoPE, fp32 pre-rounding.
  const float* nwp = (mode == 0) ? qn : kn;
  float wv[4];
#pragma unroll
  for (int nb = 0; nb < 4; ++nb) wv[nb] = nwp[nb * 16 + l16];
  const float f_th = __powf(THETA_, -(float)(l16 & 7) / 8.0f);   // t/h segs, dd=16
  const float f_w  = __powf(THETA_, -(float)l16 / 16.0f);        // w seg,  dd=32
  const float oscale = (mode == 0) ? 0.125f : 1.0f;
  const bool first8 = (l16 & 8) == 0;

  float snw[4], csw[4];
#pragma unroll
  for (int r = 0; r < 4; ++r)
    __sincosf((float)(quad * 4 + r) * f_w, &snw[r], &csw[r]);

#pragma unroll
  for (int mb = 0; mb < 2; ++mb) {
    const int nbase = (bm + w * 32 + mb * 16) & (N_ - 1);
    float snt, cst, snh, csh;
    __sincosf((float)(nbase >> 8) * f_th, &snt, &cst);
    __sincosf((float)((nbase >> 4) & 15) * f_th, &snh, &csh);
#pragma unroll
    for (int r = 0; r < 4; ++r) {
      float v[4];
      float ss = 0.f;
#pragma unroll
      for (int nb = 0; nb < 4; ++nb) { v[nb] = acc[mb][nb][r] + bsv[nb]; ss += v[nb] * v[nb]; }
      ss += __shfl_xor(ss, 1, 64);
      ss += __shfl_xor(ss, 2, 64);
      ss += __shfl_xor(ss, 4, 64);
      ss += __shfl_xor(ss, 8, 64);
      const float rs = rsqrtf(ss * (1.0f / 64.0f) + EPS_);
#pragma unroll
      for (int nb = 0; nb < 4; ++nb) v[nb] *= rs * wv[nb];

      const float p0 = __shfl_xor(v[0], 8, 64);
      const float p1 = __shfl_xor(v[1], 8, 64);
      const float o0 = v[0] * cst + (first8 ? -p0 : p0) * snt;
      const float o1 = v[1] * csh + (first8 ? -p1 : p1) * snh;
      const float o2 = v[2] * csw[r] - v[3] * snw[r];
      const float o3 = v[3] * csw[r] + v[2] * snw[r];

      const int row = bm + w * 32 + mb * 16 + quad * 4 + r;
      const size_t ob = (size_t)row * opitch + col0 + l16;
      outp[ob]      = f2h(o0 * oscale);
      outp[ob + 16] = f2h(o1 * oscale);
      outp[ob + 32] = f2h(o2 * oscale);
      outp[ob + 48] = f2h(o3 * oscale);
    }
  }
}

// ---------------------------------------------------------------------------
// Output projection: A = O (single f16), B = 64*Wo^T as f16 hi+lo (~22 bits).
// 128x64 tile (512 blocks = 2/CU), BK=64. 4 waves as 2x2 (wave = 64x32).
// Epilogue multiplies by 1/64 (exact) and adds bias.
// ---------------------------------------------------------------------------
__global__ __launch_bounds__(256) void gemm_o(
    const unsigned short* __restrict__ ag,
    const unsigned short* __restrict__ WTh, const unsigned short* __restrict__ WTl,
    const float* __restrict__ bo, float* __restrict__ out)
{
  __shared__ unsigned short As[128][72];
  __shared__ unsigned short Bh[64][72], Bl[64][72];

  const int bm = blockIdx.x * 128, bn = blockIdx.y * 64;
  const int tid = threadIdx.x;
  const int w = tid >> 6, lane = tid & 63, quad = lane >> 4, l16 = lane & 15;
  const int wm = w & 1, wn = w >> 1;
  const int sa = tid >> 1, ska = (tid & 1) * 32;
  const int sb = tid >> 2, skb = (tid & 3) * 16;

  f32x4 acc[4][2];
#pragma unroll
  for (int i = 0; i < 4; ++i)
#pragma unroll
    for (int j = 0; j < 2; ++j) acc[i][j] = (f32x4){0.f, 0.f, 0.f, 0.f};

  for (int k0 = 0; k0 < D_; k0 += 64) {
    __syncthreads();
    const size_t ga = (size_t)(bm + sa) * D_ + k0 + ska;
    const size_t gb = (size_t)(bn + sb) * D_ + k0 + skb;
#pragma unroll
    for (int j = 0; j < 4; ++j)
      *(ushort8v*)&As[sa][ska + 8 * j] = *(const ushort8v*)(ag + ga + 8 * j);
#pragma unroll
    for (int j = 0; j < 2; ++j) {
      *(ushort8v*)&Bh[sb][skb + 8 * j] = *(const ushort8v*)(WTh + gb + 8 * j);
      *(ushort8v*)&Bl[sb][skb + 8 * j] = *(const ushort8v*)(WTl + gb + 8 * j);
    }
    __syncthreads();

#pragma unroll
    for (int kk = 0; kk < 2; ++kk) {
      half8v fa[4], fbh[2], fbl[2];
#pragma unroll
      for (int mb = 0; mb < 4; ++mb) fa[mb] = *(const half8v*)&As[wm * 64 + mb * 16 + l16][kk * 32 + quad * 8];
#pragma unroll
      for (int nb = 0; nb < 2; ++nb) {
        fbh[nb] = *(const half8v*)&Bh[wn * 32 + nb * 16 + l16][kk * 32 + quad * 8];
        fbl[nb] = *(const half8v*)&Bl[wn * 32 + nb * 16 + l16][kk * 32 + quad * 8];
      }
#pragma unroll
      for (int mb = 0; mb < 4; ++mb)
#pragma unroll
        for (int nb = 0; nb < 2; ++nb) {
          acc[mb][nb] = __builtin_amdgcn_mfma_f32_16x16x32_f16(fa[mb], fbl[nb], acc[mb][nb], 0, 0, 0);
          acc[mb][nb] = __builtin_amdgcn_mfma_f32_16x16x32_f16(fa[mb], fbh[nb], acc[mb][nb], 0, 0, 0);
        }
    }
  }

  float bsv[2];
#pragma unroll
  for (int nb = 0; nb < 2; ++nb) bsv[nb] = bo[bn + wn * 32 + nb * 16 + l16];
#pragma unroll
  for (int mb = 0; mb < 4; ++mb)
#pragma unroll
    for (int nb = 0; nb < 2; ++nb)
#pragma unroll
      for (int r = 0; r < 4; ++r) {
        const int row = bm + wm * 64 + mb * 16 + quad * 4 + r;
        const int col = bn + wn * 32 + nb * 16 + l16;
        out[(size_t)row * D_ + col] = acc[mb][nb][r] * 0.015625f + bsv[nb];
      }
}

// ---------------------------------------------------------------------------
// MFMA flash attention, all-f16, no-max softmax (|s| <= 8 by Cauchy-Schwarz on
// unit-RMS q,k). 4 waves x 32 q-rows (r7 structure) but 128 KEYS PER ITERATION:
// 16 loop iterations instead of 32 -> half the barriers / staging rounds (the
// measured serialization). S->P->PV runs per 64-key half, reusing the per-wave
// P buffer (no barrier needed: wave-private). LDS = 54.3 KB -> 2 blocks/CU.
// ---------------------------------------------------------------------------
__global__ __launch_bounds__(256) void attn_mfma(
    const unsigned short* __restrict__ qg,
    const unsigned short* __restrict__ kg,
    const unsigned short* __restrict__ vg,
    unsigned short* __restrict__ og)
{
  __shared__ unsigned short Ks[128][72];
  __shared__ unsigned short Vt[64][136];     // [dim][key'], 128 keys
  __shared__ unsigned short Pw[4][32][72];   // per-wave P (one 64-key half)

  const int bid = blockIdx.x;
  const int qt  = bid & 15;
  const int h   = (bid >> 4) & 15;
  const int b   = bid >> 8;
  const int kvh = h >> 2;            // GQA: q-head h -> kv-head h/4

  const int tid  = threadIdx.x;
  const int w    = tid >> 6;         // 0..3
  const int lane = tid & 63;
  const int quad = lane >> 4;
  const int l16  = lane & 15;

  // Q A-frags for 2 query sets; 0.125 scale already folded into q.
  half8v aq[2][2];
#pragma unroll
  for (int qb = 0; qb < 2; ++qb) {
    const int qrow = qt * 128 + w * 32 + qb * 16 + l16;
    const unsigned short* qptr =
        qg + ((size_t)(b * N_ + qrow) * D_) + h * HD_ + quad * 8;
    aq[qb][0] = *(const half8v*)(qptr);
    aq[qb][1] = *(const half8v*)(qptr + 32);
  }

  f32x4 o[2][4];
  float lrow[2][4];
#pragma unroll
  for (int qb = 0; qb < 2; ++qb)
#pragma unroll
    for (int i = 0; i < 4; ++i) { o[qb][i] = (f32x4){0.f, 0.f, 0.f, 0.f}; lrow[qb][i] = 0.f; }

  // K staging: rows srow, srow+64; 16-dim segment (tid&3)*16
  const int srow = tid >> 2;
  const int sseg = (tid & 3) << 4;
  // V staging: keys vj+32vh & +16 per half -> key' cols 64*hh+4vj+2vh(+1)
  const int vj = tid & 15;
  const int vh = (tid >> 4) & 1;
  const int vs = tid >> 5;           // 0..7

  for (int kt = 0; kt < 16; ++kt) {
    const int kbase = kt * 128;
    __syncthreads();
    {
#pragma unroll
      for (int rr = 0; rr < 2; ++rr) {
        const int row = srow + rr * 64;
        const unsigned short* ksrc =
            kg + (size_t)(b * N_ + kbase + row) * KVD_ + kvh * HD_ + sseg;
        *(ushort8v*)&Ks[row][sseg]     = *(const ushort8v*)(ksrc);
        *(ushort8v*)&Ks[row][sseg + 8] = *(const ushort8v*)(ksrc + 8);
      }
#pragma unroll
      for (int hh = 0; hh < 2; ++hh) {
        const unsigned short* v1 =
            vg + (size_t)(b * N_ + kbase + hh * 64 + vj + 32 * vh) * KVD_ + kvh * HD_ + 8 * vs;
        const ushort8v va = *(const ushort8v*)(v1);
        const ushort8v vb8 = *(const ushort8v*)(v1 + 16 * KVD_);
        const int vcol = hh * 64 + 4 * vj + 2 * vh;
#pragma unroll
        for (int i = 0; i < 8; ++i)
          *(unsigned int*)&Vt[8 * vs + i][vcol] =
              (unsigned int)va[i] | ((unsigned int)vb8[i] << 16);
      }
    }
    __syncthreads();

#pragma unroll
    for (int hh = 0; hh < 2; ++hh) {
      // S = Q K^T for this 64-key half
      f32x4 s[2][4];
#pragma unroll
      for (int nb = 0; nb < 4; ++nb) {
        const half8v b0 = *(const half8v*)&Ks[hh * 64 + nb * 16 + l16][quad * 8];
        const half8v b1 = *(const half8v*)&Ks[hh * 64 + nb * 16 + l16][32 + quad * 8];
#pragma unroll
        for (int qb = 0; qb < 2; ++qb) {
          f32x4 z = (f32x4){0.f, 0.f, 0.f, 0.f};
          z = __builtin_amdgcn_mfma_f32_16x16x32_f16(aq[qb][0], b0, z, 0, 0, 0);
          s[qb][nb] = __builtin_amdgcn_mfma_f32_16x16x32_f16(aq[qb][1], b1, z, 0, 0, 0);
        }
      }

      // p = exp(s) (bounded); pack 4 keys' -> one b64 per row (wave-private P)
#pragma unroll
      for (int qb = 0; qb < 2; ++qb)
#pragma unroll
        for (int r = 0; r < 4; ++r) {
          const float p0 = __expf(s[qb][0][r]);
          const float p1 = __expf(s[qb][1][r]);
          const float p2 = __expf(s[qb][2][r]);
          const float p3 = __expf(s[qb][3][r]);
          lrow[qb][r] += (p0 + p1) + (p2 + p3);
          uint2 u;
          u.x = (unsigned int)f2h(p0) | ((unsigned int)f2h(p1) << 16);
          u.y = (unsigned int)f2h(p2) | ((unsigned int)f2h(p3) << 16);
          *(uint2*)&Pw[w][qb * 16 + quad * 4 + r][4 * l16] = u;
        }

      // O += P V for this half (key' order on both sides)
#pragma unroll
      for (int kc = 0; kc < 2; ++kc) {
        half8v ap[2];
#pragma unroll
        for (int qb = 0; qb < 2; ++qb)
          ap[qb] = *(const half8v*)&Pw[w][qb * 16 + l16][kc * 32 + quad * 8];
#pragma unroll
        for (int nb = 0; nb < 4; ++nb) {
          const half8v bv = *(const half8v*)&Vt[nb * 16 + l16][hh * 64 + kc * 32 + quad * 8];
#pragma unroll
          for (int qb = 0; qb < 2; ++qb)
            o[qb][nb] = __builtin_amdgcn_mfma_f32_16x16x32_f16(ap[qb], bv, o[qb][nb], 0, 0, 0);
        }
      }
    }
  }

  // deferred l reduction + epilogue per query set
#pragma unroll
  for (int qb = 0; qb < 2; ++qb) {
#pragma unroll
    for (int r = 0; r < 4; ++r) {
      float lr = lrow[qb][r];
      lr += __shfl_xor(lr, 1, 64);
      lr += __shfl_xor(lr, 2, 64);
      lr += __shfl_xor(lr, 4, 64);
      lr += __shfl_xor(lr, 8, 64);
      lrow[qb][r] = 1.0f / lr;
    }
    const size_t obase =
        ((size_t)(b * N_ + qt * 128 + w * 32 + qb * 16 + quad * 4) * D_) +
        h * HD_ + l16;
#pragma unroll
    for (int r = 0; r < 4; ++r)
#pragma unroll
      for (int nb = 0; nb < 4; ++nb)
        og[obase + (size_t)r * D_ + nb * 16] = f2h(o[qb][nb][r] * lrow[qb][r]);
  }
}

// ---------------------------------------------------------------------------
extern "C" void kernel_launch(void* const* d_in, const int* in_sizes, int n_in,
                              void* d_out, int out_size, void* d_ws, size_t ws_size,
                              hipStream_t stream) {
  const float* x  = (const float*)d_in[0];
  const float* Wq = (const float*)d_in[1];
  const float* bq = (const float*)d_in[2];
  const float* Wk = (const float*)d_in[3];
  const float* bk = (const float*)d_in[4];
  const float* Wv = (const float*)d_in[5];
  const float* bv = (const float*)d_in[6];
  const float* Wo = (const float*)d_in[7];
  const float* bo = (const float*)d_in[8];
  const float* qn = (const float*)d_in[9];
  const float* kn = (const float*)d_in[10];
  float* out = (float*)d_out;

  // Workspace (u16 units, ~27 MB):
  //  xh(4M) qv(4M) kv(1M) vv(1M) WqT(1M) WkT(.25M) WvT(.25M) WoTh(1M) WoTl(1M)
  //  attention output og aliases xh (dead after gemm_qkv).
  const size_t M4 = (size_t)BN_ * D_;
  const size_t M1 = (size_t)BN_ * KVD_;
  unsigned short* xh  = (unsigned short*)d_ws;
  unsigned short* qv  = xh + M4;
  unsigned short* kv  = qv + M4;
  unsigned short* vv  = kv + M1;
  unsigned short* WqT = vv + M1;
  unsigned short* WkT = WqT + (size_t)D_ * D_;
  unsigned short* WvT = WkT + (size_t)D_ * KVD_;
  unsigned short* WoTh = WvT + (size_t)D_ * KVD_;
  unsigned short* WoTl = WoTh + (size_t)D_ * D_;
  unsigned short* og  = xh;   // alias

  const dim3 blk(256);

  // 1) cast + all weight transposes in one launch
  prep<<<dim3(4608), blk, 0, stream>>>(x, Wq, Wk, Wv, Wo, xh, WqT, WkT, WvT, WoTh, WoTl);

  // 2) fused QKV projection + RMSNorm + RoPE (128x64 tiles, 768 blocks)
  gemm_qkv<<<dim3(32, 24), blk, 0, stream>>>(xh, WqT, WkT, WvT, bq, bk, bv, qn, kn, qv, kv, vv);

  // 3) all-f16 MFMA flash attention (128 keys/iteration, 512 blocks)
  attn_mfma<<<dim3(B_ * NH_ * (N_ / 128)), blk, 0, stream>>>(qv, kv, vv, og);

  // 4) output projection (128x64 tiles, 512 blocks)
  gemm_o<<<dim3(32, 16), blk, 0, stream>>>(og, WoTh, WoTl, bo, out);
}

// Round 10
// 198.041 us; speedup vs baseline: 1.2079x; 1.1407x over previous
//
#include <hip/hip_runtime.h>
#include <hip/hip_bf16.h>
#include <math.h>

// Problem constants (fixed by the reference file)
constexpr int B_   = 2;
constexpr int N_   = 2048;   // T*HS*WS = 8*16*16
constexpr int D_   = 1024;
constexpr int NH_  = 16;
constexpr int NKV_ = 4;
constexpr int HD_  = 64;
constexpr int BN_  = 4096;   // B_*N_
constexpr int KVD_ = NKV_ * HD_;  // 256
constexpr float EPS_ = 1e-6f;
constexpr float THETA_ = 10000.0f;

typedef _Float16 half8v __attribute__((ext_vector_type(8)));
typedef unsigned short ushort8v __attribute__((ext_vector_type(8)));
typedef float f32x4 __attribute__((ext_vector_type(4)));

static __device__ __forceinline__ unsigned short f2h(float f) {
  union { _Float16 h; unsigned short u; } v; v.h = (_Float16)f; return v.u;
}
static __device__ __forceinline__ float h2f(unsigned short u) {
  union { unsigned short u; _Float16 h; } v; v.u = u; return (float)v.h;
}

// global -> LDS direct DMA, 16 B per lane. LDS dest = wave-uniform base +
// lane*16 (m104). The per-lane GLOBAL address is free, which lets us store an
// XOR-swizzled layout (chunk c of row r lands at slot c^(r&7)) so the b128
// fragment reads are conflict-free without padding.
static __device__ __forceinline__ void dma16(const unsigned short* g,
                                             unsigned short* l) {
  __builtin_amdgcn_global_load_lds(
      (const __attribute__((address_space(1))) unsigned int*)g,
      (__attribute__((address_space(3))) unsigned int*)l, 16, 0, 0);
}

// ---------------------------------------------------------------------------
// prep: one launch doing x->f16 cast + all 4 weight transposes (f16; Wo hi/lo
// with x64 pre-scale). Linear block-id partition.
// ---------------------------------------------------------------------------
static __device__ __forceinline__ void wtrans_tile(
    const float* __restrict__ W, int Nw, int K, float scale,
    unsigned short* __restrict__ WTh, unsigned short* __restrict__ WTl,
    int bx, int by, bool lo)
{
  __shared__ float tile[32][33];
  const int k0 = bx * 32, n0 = by * 32;
  const int c = threadIdx.x & 31, rb = threadIdx.x >> 5;
#pragma unroll
  for (int i = 0; i < 4; ++i) {
    const int r = rb + i * 8;
    tile[r][c] = W[(size_t)(k0 + r) * Nw + n0 + c];
  }
  __syncthreads();
#pragma unroll
  for (int i = 0; i < 4; ++i) {
    const int r = rb + i * 8;
    const float v = tile[c][r] * scale;   // = W[k0+c][n0+r] * scale
    const size_t o = (size_t)(n0 + r) * K + k0 + c;
    const unsigned short hi = f2h(v);
    WTh[o] = hi;
    if (lo) WTl[o] = f2h(v - h2f(hi));
  }
}

__global__ __launch_bounds__(256) void prep(
    const float* __restrict__ x,
    const float* __restrict__ Wq, const float* __restrict__ Wk,
    const float* __restrict__ Wv, const float* __restrict__ Wo,
    unsigned short* __restrict__ xh,
    unsigned short* __restrict__ WqT, unsigned short* __restrict__ WkT,
    unsigned short* __restrict__ WvT,
    unsigned short* __restrict__ WoTh, unsigned short* __restrict__ WoTl)
{
  const int bid = blockIdx.x;
  if (bid < 2048) {
    const int i = (bid * 256 + threadIdx.x) * 8;
    const float4 v0 = *(const float4*)(x + i);
    const float4 v1 = *(const float4*)(x + i + 4);
    ushort8v o;
    o[0] = f2h(v0.x); o[1] = f2h(v0.y); o[2] = f2h(v0.z); o[3] = f2h(v0.w);
    o[4] = f2h(v1.x); o[5] = f2h(v1.y); o[6] = f2h(v1.z); o[7] = f2h(v1.w);
    *(ushort8v*)(xh + i) = o;
  } else if (bid < 3072) {
    const int l = bid - 2048;
    wtrans_tile(Wq, D_, D_, 1.0f, WqT, nullptr, l & 31, l >> 5, false);
  } else if (bid < 3328) {
    const int l = bid - 3072;
    wtrans_tile(Wk, KVD_, D_, 1.0f, WkT, nullptr, l & 31, l >> 5, false);
  } else if (bid < 3584) {
    const int l = bid - 3328;
    wtrans_tile(Wv, KVD_, D_, 1.0f, WvT, nullptr, l & 31, l >> 5, false);
  } else {
    const int l = bid - 3584;
    wtrans_tile(Wo, D_, D_, 64.0f, WoTh, WoTl, l & 31, l >> 5, true);
  }
}

// ---------------------------------------------------------------------------
// Fused QKV projection + RMSNorm + 3D RoPE in the epilogue.
// 128x64 tile (768 blocks = 3/CU), BK=64. 4 waves all-M (32 rows each, full
// 64-col head per wave). m97-style staging: global_load_lds width 16 into
// XOR-swizzled unpadded LDS; ds_read_b128 frags are conflict-free.
// ---------------------------------------------------------------------------
__global__ __launch_bounds__(256) void gemm_qkv(
    const unsigned short* __restrict__ xh,
    const unsigned short* __restrict__ WqT, const unsigned short* __restrict__ WkT,
    const unsigned short* __restrict__ WvT,
    const float* __restrict__ bq, const float* __restrict__ bk, const float* __restrict__ bv,
    const float* __restrict__ qn, const float* __restrict__ kn,
    unsigned short* __restrict__ qv, unsigned short* __restrict__ kv,
    unsigned short* __restrict__ vv)
{
  __shared__ unsigned short As[128 * 64];   // swizzled, 16 KB
  __shared__ unsigned short Bs[64 * 64];    // swizzled, 8 KB

  const int y = blockIdx.y;
  const unsigned short* wt; const float* bias; unsigned short* outp; int opitch, col0, mode;
  if (y < 16)      { wt = WqT + (size_t)y * 64 * D_;        bias = bq + y * 64;        outp = qv; opitch = D_;   col0 = y * 64;        mode = 0; }
  else if (y < 20) { wt = WkT + (size_t)(y - 16) * 64 * D_; bias = bk + (y - 16) * 64; outp = kv; opitch = KVD_; col0 = (y - 16) * 64; mode = 1; }
  else             { wt = WvT + (size_t)(y - 20) * 64 * D_; bias = bv + (y - 20) * 64; outp = vv; opitch = KVD_; col0 = (y - 20) * 64; mode = 2; }

  const int bm = blockIdx.x * 128;
  const int tid = threadIdx.x;
  const int w = tid >> 6, lane = tid & 63, quad = lane >> 4, l16 = lane & 15;
  const int lr = lane >> 3;          // staged sub-row 0..7
  const int gc = (lane & 7) ^ lr;    // swizzled source chunk
  const int sw = l16 & 7;            // frag-read swizzle selector

  // per-lane global element offsets (row advances by rd*32 / k0 in the loop)
  const unsigned short* gA = xh + (size_t)(bm + w * 8 + lr) * D_ + gc * 8;
  const unsigned short* gB = wt + (size_t)(w * 8 + lr) * D_ + gc * 8;

  f32x4 acc[2][4];
#pragma unroll
  for (int i = 0; i < 2; ++i)
#pragma unroll
    for (int j = 0; j < 4; ++j) acc[i][j] = (f32x4){0.f, 0.f, 0.f, 0.f};

  for (int k0 = 0; k0 < D_; k0 += 64) {
    __syncthreads();
#pragma unroll
    for (int rd = 0; rd < 4; ++rd)
      dma16(gA + (size_t)rd * 32 * D_ + k0, &As[rd * 2048 + w * 512]);
#pragma unroll
    for (int rd = 0; rd < 2; ++rd)
      dma16(gB + (size_t)rd * 32 * D_ + k0, &Bs[rd * 2048 + w * 512]);
    __syncthreads();

#pragma unroll
    for (int kk = 0; kk < 2; ++kk) {
      half8v fa[2], fb[4];
#pragma unroll
      for (int mb = 0; mb < 2; ++mb)
        fa[mb] = *(const half8v*)&As[(w * 32 + mb * 16 + l16) * 64 + ((kk * 4 + quad) ^ sw) * 8];
#pragma unroll
      for (int nb = 0; nb < 4; ++nb)
        fb[nb] = *(const half8v*)&Bs[(nb * 16 + l16) * 64 + ((kk * 4 + quad) ^ sw) * 8];
#pragma unroll
      for (int mb = 0; mb < 2; ++mb)
#pragma unroll
        for (int nb = 0; nb < 4; ++nb)
          acc[mb][nb] = __builtin_amdgcn_mfma_f32_16x16x32_f16(fa[mb], fb[nb], acc[mb][nb], 0, 0, 0);
    }
  }

  float bsv[4];
#pragma unroll
  for (int nb = 0; nb < 4; ++nb) bsv[nb] = bias[nb * 16 + l16];

  if (mode == 2) {   // V: bias + cast only
#pragma unroll
    for (int mb = 0; mb < 2; ++mb)
#pragma unroll
      for (int nb = 0; nb < 4; ++nb)
#pragma unroll
        for (int r = 0; r < 4; ++r) {
          const int row = bm + w * 32 + mb * 16 + quad * 4 + r;
          outp[(size_t)row * opitch + col0 + nb * 16 + l16] = f2h(acc[mb][nb][r] + bsv[nb]);
        }
    return;
  }

  // Q/K: RMSNorm (+learned w) + factored 3D RoPE, fp32 pre-rounding.
  const float* nwp = (mode == 0) ? qn : kn;
  float wv[4];
#pragma unroll
  for (int nb = 0; nb < 4; ++nb) wv[nb] = nwp[nb * 16 + l16];
  const float f_th = __powf(THETA_, -(float)(l16 & 7) / 8.0f);   // t/h segs, dd=16
  const float f_w  = __powf(THETA_, -(float)l16 / 16.0f);        // w seg,  dd=32
  const float oscale = (mode == 0) ? 0.125f : 1.0f;
  const bool first8 = (l16 & 8) == 0;

  float snw[4], csw[4];
#pragma unroll
  for (int r = 0; r < 4; ++r)
    __sincosf((float)(quad * 4 + r) * f_w, &snw[r], &csw[r]);

#pragma unroll
  for (int mb = 0; mb < 2; ++mb) {
    const int nbase = (bm + w * 32 + mb * 16) & (N_ - 1);
    float snt, cst, snh, csh;
    __sincosf((float)(nbase >> 8) * f_th, &snt, &cst);
    __sincosf((float)((nbase >> 4) & 15) * f_th, &snh, &csh);
#pragma unroll
    for (int r = 0; r < 4; ++r) {
      float v[4];
      float ss = 0.f;
#pragma unroll
      for (int nb = 0; nb < 4; ++nb) { v[nb] = acc[mb][nb][r] + bsv[nb]; ss += v[nb] * v[nb]; }
      ss += __shfl_xor(ss, 1, 64);
      ss += __shfl_xor(ss, 2, 64);
      ss += __shfl_xor(ss, 4, 64);
      ss += __shfl_xor(ss, 8, 64);
      const float rs = rsqrtf(ss * (1.0f / 64.0f) + EPS_);
#pragma unroll
      for (int nb = 0; nb < 4; ++nb) v[nb] *= rs * wv[nb];

      const float p0 = __shfl_xor(v[0], 8, 64);
      const float p1 = __shfl_xor(v[1], 8, 64);
      const float o0 = v[0] * cst + (first8 ? -p0 : p0) * snt;
      const float o1 = v[1] * csh + (first8 ? -p1 : p1) * snh;
      const float o2 = v[2] * csw[r] - v[3] * snw[r];
      const float o3 = v[3] * csw[r] + v[2] * snw[r];

      const int row = bm + w * 32 + mb * 16 + quad * 4 + r;
      const size_t ob = (size_t)row * opitch + col0 + l16;
      outp[ob]      = f2h(o0 * oscale);
      outp[ob + 16] = f2h(o1 * oscale);
      outp[ob + 32] = f2h(o2 * oscale);
      outp[ob + 48] = f2h(o3 * oscale);
    }
  }
}

// ---------------------------------------------------------------------------
// Output projection: A = O (single f16), B = 64*Wo^T as f16 hi+lo (~22 bits).
// 128x64 tile (512 blocks), BK=64, 4 waves all-M. Same DMA+swizzle staging.
// Epilogue multiplies by 1/64 (exact) and adds bias.
// ---------------------------------------------------------------------------
__global__ __launch_bounds__(256) void gemm_o(
    const unsigned short* __restrict__ ag,
    const unsigned short* __restrict__ WTh, const unsigned short* __restrict__ WTl,
    const float* __restrict__ bo, float* __restrict__ out)
{
  __shared__ unsigned short As[128 * 64];
  __shared__ unsigned short Bh[64 * 64], Bl[64 * 64];

  const int bm = blockIdx.x * 128, bn = blockIdx.y * 64;
  const int tid = threadIdx.x;
  const int w = tid >> 6, lane = tid & 63, quad = lane >> 4, l16 = lane & 15;
  const int lr = lane >> 3;
  const int gc = (lane & 7) ^ lr;
  const int sw = l16 & 7;

  const unsigned short* gA  = ag  + (size_t)(bm + w * 8 + lr) * D_ + gc * 8;
  const unsigned short* gBh = WTh + (size_t)(bn + w * 8 + lr) * D_ + gc * 8;
  const unsigned short* gBl = WTl + (size_t)(bn + w * 8 + lr) * D_ + gc * 8;

  f32x4 acc[2][4];
#pragma unroll
  for (int i = 0; i < 2; ++i)
#pragma unroll
    for (int j = 0; j < 4; ++j) acc[i][j] = (f32x4){0.f, 0.f, 0.f, 0.f};

  for (int k0 = 0; k0 < D_; k0 += 64) {
    __syncthreads();
#pragma unroll
    for (int rd = 0; rd < 4; ++rd)
      dma16(gA + (size_t)rd * 32 * D_ + k0, &As[rd * 2048 + w * 512]);
#pragma unroll
    for (int rd = 0; rd < 2; ++rd) {
      dma16(gBh + (size_t)rd * 32 * D_ + k0, &Bh[rd * 2048 + w * 512]);
      dma16(gBl + (size_t)rd * 32 * D_ + k0, &Bl[rd * 2048 + w * 512]);
    }
    __syncthreads();

#pragma unroll
    for (int kk = 0; kk < 2; ++kk) {
      half8v fa[2], fbh[4], fbl[4];
#pragma unroll
      for (int mb = 0; mb < 2; ++mb)
        fa[mb] = *(const half8v*)&As[(w * 32 + mb * 16 + l16) * 64 + ((kk * 4 + quad) ^ sw) * 8];
#pragma unroll
      for (int nb = 0; nb < 4; ++nb) {
        const int ro = (nb * 16 + l16) * 64 + ((kk * 4 + quad) ^ sw) * 8;
        fbh[nb] = *(const half8v*)&Bh[ro];
        fbl[nb] = *(const half8v*)&Bl[ro];
      }
#pragma unroll
      for (int mb = 0; mb < 2; ++mb)
#pragma unroll
        for (int nb = 0; nb < 4; ++nb) {
          acc[mb][nb] = __builtin_amdgcn_mfma_f32_16x16x32_f16(fa[mb], fbl[nb], acc[mb][nb], 0, 0, 0);
          acc[mb][nb] = __builtin_amdgcn_mfma_f32_16x16x32_f16(fa[mb], fbh[nb], acc[mb][nb], 0, 0, 0);
        }
    }
  }

  float bsv[4];
#pragma unroll
  for (int nb = 0; nb < 4; ++nb) bsv[nb] = bo[bn + nb * 16 + l16];
#pragma unroll
  for (int mb = 0; mb < 2; ++mb)
#pragma unroll
    for (int nb = 0; nb < 4; ++nb)
#pragma unroll
      for (int r = 0; r < 4; ++r) {
        const int row = bm + w * 32 + mb * 16 + quad * 4 + r;
        const int col = bn + nb * 16 + l16;
        out[(size_t)row * D_ + col] = acc[mb][nb][r] * 0.015625f + bsv[nb];
      }
}

// ---------------------------------------------------------------------------
// MFMA flash attention (r9 structure: 4 waves x 32 q-rows, 128 keys/iter,
// no-max softmax). K staging now via global_load_lds into swizzled unpadded
// LDS (conflict-free b128 frag reads); V transpose staging unchanged.
// ---------------------------------------------------------------------------
__global__ __launch_bounds__(256) void attn_mfma(
    const unsigned short* __restrict__ qg,
    const unsigned short* __restrict__ kg,
    const unsigned short* __restrict__ vg,
    unsigned short* __restrict__ og)
{
  __shared__ unsigned short Ks[128 * 64];    // swizzled, 16 KB
  __shared__ unsigned short Vt[64][136];     // [dim][key'], 128 keys
  __shared__ unsigned short Pw[4][32][72];   // per-wave P (one 64-key half)

  const int bid = blockIdx.x;
  const int qt  = bid & 15;
  const int h   = (bid >> 4) & 15;
  const int b   = bid >> 8;
  const int kvh = h >> 2;            // GQA: q-head h -> kv-head h/4

  const int tid  = threadIdx.x;
  const int w    = tid >> 6;         // 0..3
  const int lane = tid & 63;
  const int quad = lane >> 4;
  const int l16  = lane & 15;
  const int lr = lane >> 3;
  const int gc = (lane & 7) ^ lr;
  const int sw = l16 & 7;

  // Q A-frags for 2 query sets; 0.125 scale already folded into q.
  half8v aq[2][2];
#pragma unroll
  for (int qb = 0; qb < 2; ++qb) {
    const int qrow = qt * 128 + w * 32 + qb * 16 + l16;
    const unsigned short* qptr =
        qg + ((size_t)(b * N_ + qrow) * D_) + h * HD_ + quad * 8;
    aq[qb][0] = *(const half8v*)(qptr);
    aq[qb][1] = *(const half8v*)(qptr + 32);
  }

  f32x4 o[2][4];
  float lrow[2][4];
#pragma unroll
  for (int qb = 0; qb < 2; ++qb)
#pragma unroll
    for (int i = 0; i < 4; ++i) { o[qb][i] = (f32x4){0.f, 0.f, 0.f, 0.f}; lrow[qb][i] = 0.f; }

  // K DMA source (row advances by kbase + rd*32 in the loop)
  const unsigned short* gK =
      kg + ((size_t)(b * N_) + w * 8 + lr) * KVD_ + kvh * HD_ + gc * 8;
  // V staging: keys vj+32vh & +16 per half -> key' cols 64*hh+4vj+2vh(+1)
  const int vj = tid & 15;
  const int vh = (tid >> 4) & 1;
  const int vs = tid >> 5;           // 0..7

  for (int kt = 0; kt < 16; ++kt) {
    const int kbase = kt * 128;
    __syncthreads();
    {
#pragma unroll
      for (int rd = 0; rd < 4; ++rd)
        dma16(gK + (size_t)(kbase + rd * 32) * KVD_, &Ks[rd * 2048 + w * 512]);
#pragma unroll
      for (int hh = 0; hh < 2; ++hh) {
        const unsigned short* v1 =
            vg + (size_t)(b * N_ + kbase + hh * 64 + vj + 32 * vh) * KVD_ + kvh * HD_ + 8 * vs;
        const ushort8v va = *(const ushort8v*)(v1);
        const ushort8v vb8 = *(const ushort8v*)(v1 + 16 * KVD_);
        const int vcol = hh * 64 + 4 * vj + 2 * vh;
#pragma unroll
        for (int i = 0; i < 8; ++i)
          *(unsigned int*)&Vt[8 * vs + i][vcol] =
              (unsigned int)va[i] | ((unsigned int)vb8[i] << 16);
      }
    }
    __syncthreads();

#pragma unroll
    for (int hh = 0; hh < 2; ++hh) {
      // S = Q K^T for this 64-key half
      f32x4 s[2][4];
#pragma unroll
      for (int nb = 0; nb < 4; ++nb) {
        const int kr = (hh * 64 + nb * 16 + l16) * 64;
        const half8v b0 = *(const half8v*)&Ks[kr + (quad ^ sw) * 8];
        const half8v b1 = *(const half8v*)&Ks[kr + ((4 + quad) ^ sw) * 8];
#pragma unroll
        for (int qb = 0; qb < 2; ++qb) {
          f32x4 z = (f32x4){0.f, 0.f, 0.f, 0.f};
          z = __builtin_amdgcn_mfma_f32_16x16x32_f16(aq[qb][0], b0, z, 0, 0, 0);
          s[qb][nb] = __builtin_amdgcn_mfma_f32_16x16x32_f16(aq[qb][1], b1, z, 0, 0, 0);
        }
      }

      // p = exp(s) (bounded); pack 4 keys' -> one b64 per row (wave-private P)
#pragma unroll
      for (int qb = 0; qb < 2; ++qb)
#pragma unroll
        for (int r = 0; r < 4; ++r) {
          const float p0 = __expf(s[qb][0][r]);
          const float p1 = __expf(s[qb][1][r]);
          const float p2 = __expf(s[qb][2][r]);
          const float p3 = __expf(s[qb][3][r]);
          lrow[qb][r] += (p0 + p1) + (p2 + p3);
          uint2 u;
          u.x = (unsigned int)f2h(p0) | ((unsigned int)f2h(p1) << 16);
          u.y = (unsigned int)f2h(p2) | ((unsigned int)f2h(p3) << 16);
          *(uint2*)&Pw[w][qb * 16 + quad * 4 + r][4 * l16] = u;
        }

      // O += P V for this half (key' order on both sides)
#pragma unroll
      for (int kc = 0; kc < 2; ++kc) {
        half8v ap[2];
#pragma unroll
        for (int qb = 0; qb < 2; ++qb)
          ap[qb] = *(const half8v*)&Pw[w][qb * 16 + l16][kc * 32 + quad * 8];
#pragma unroll
        for (int nb = 0; nb < 4; ++nb) {
          const half8v bv = *(const half8v*)&Vt[nb * 16 + l16][hh * 64 + kc * 32 + quad * 8];
#pragma unroll
          for (int qb = 0; qb < 2; ++qb)
            o[qb][nb] = __builtin_amdgcn_mfma_f32_16x16x32_f16(ap[qb], bv, o[qb][nb], 0, 0, 0);
        }
      }
    }
  }

  // deferred l reduction + epilogue per query set
#pragma unroll
  for (int qb = 0; qb < 2; ++qb) {
#pragma unroll
    for (int r = 0; r < 4; ++r) {
      float lr2 = lrow[qb][r];
      lr2 += __shfl_xor(lr2, 1, 64);
      lr2 += __shfl_xor(lr2, 2, 64);
      lr2 += __shfl_xor(lr2, 4, 64);
      lr2 += __shfl_xor(lr2, 8, 64);
      lrow[qb][r] = 1.0f / lr2;
    }
    const size_t obase =
        ((size_t)(b * N_ + qt * 128 + w * 32 + qb * 16 + quad * 4) * D_) +
        h * HD_ + l16;
#pragma unroll
    for (int r = 0; r < 4; ++r)
#pragma unroll
      for (int nb = 0; nb < 4; ++nb)
        og[obase + (size_t)r * D_ + nb * 16] = f2h(o[qb][nb][r] * lrow[qb][r]);
  }
}

// ---------------------------------------------------------------------------
extern "C" void kernel_launch(void* const* d_in, const int* in_sizes, int n_in,
                              void* d_out, int out_size, void* d_ws, size_t ws_size,
                              hipStream_t stream) {
  const float* x  = (const float*)d_in[0];
  const float* Wq = (const float*)d_in[1];
  const float* bq = (const float*)d_in[2];
  const float* Wk = (const float*)d_in[3];
  const float* bk = (const float*)d_in[4];
  const float* Wv = (const float*)d_in[5];
  const float* bv = (const float*)d_in[6];
  const float* Wo = (const float*)d_in[7];
  const float* bo = (const float*)d_in[8];
  const float* qn = (const float*)d_in[9];
  const float* kn = (const float*)d_in[10];
  float* out = (float*)d_out;

  // Workspace (u16 units, ~27 MB):
  //  xh(4M) qv(4M) kv(1M) vv(1M) WqT(1M) WkT(.25M) WvT(.25M) WoTh(1M) WoTl(1M)
  //  attention output og aliases xh (dead after gemm_qkv).
  const size_t M4 = (size_t)BN_ * D_;
  const size_t M1 = (size_t)BN_ * KVD_;
  unsigned short* xh  = (unsigned short*)d_ws;
  unsigned short* qv  = xh + M4;
  unsigned short* kv  = qv + M4;
  unsigned short* vv  = kv + M1;
  unsigned short* WqT = vv + M1;
  unsigned short* WkT = WqT + (size_t)D_ * D_;
  unsigned short* WvT = WkT + (size_t)D_ * KVD_;
  unsigned short* WoTh = WvT + (size_t)D_ * KVD_;
  unsigned short* WoTl = WoTh + (size_t)D_ * D_;
  unsigned short* og  = xh;   // alias

  const dim3 blk(256);

  // 1) cast + all weight transposes in one launch
  prep<<<dim3(4608), blk, 0, stream>>>(x, Wq, Wk, Wv, Wo, xh, WqT, WkT, WvT, WoTh, WoTl);

  // 2) fused QKV projection + RMSNorm + RoPE (DMA-staged, 768 blocks)
  gemm_qkv<<<dim3(32, 24), blk, 0, stream>>>(xh, WqT, WkT, WvT, bq, bk, bv, qn, kn, qv, kv, vv);

  // 3) all-f16 MFMA flash attention (K DMA-staged, 512 blocks)
  attn_mfma<<<dim3(B_ * NH_ * (N_ / 128)), blk, 0, stream>>>(qv, kv, vv, og);

  // 4) output projection (DMA-staged, 512 blocks)
  gemm_o<<<dim3(32, 16), blk, 0, stream>>>(og, WoTh, WoTl, bo, out);
}